// Round 9
// baseline (555.152 us; speedup 1.0000x reference)
//
#include <hip/hip_runtime.h>
#include <hip/hip_bf16.h>

#define NCODES 8192
#define CDIM 128
#define NTOT (16*128*32*32)   // 2097152

typedef __attribute__((ext_vector_type(8))) short bf16x8;
typedef __attribute__((ext_vector_type(16))) float f32x16;
typedef unsigned long long u64;
typedef unsigned int u32;
typedef unsigned short ushort_t;

__device__ __forceinline__ ushort_t f2bf(float x) {
    u32 u = __float_as_uint(x);
    u32 r = (u + 0x7FFFu + ((u >> 16) & 1u)) >> 16;
    return (ushort_t)r;
}
__device__ __forceinline__ float bf2f(ushort_t h) {
    return __uint_as_float(((u32)h) << 16);
}

__device__ __forceinline__ void gload_lds16(const void* g, void* l) {
    __builtin_amdgcn_global_load_lds(
        (const __attribute__((address_space(1))) unsigned int*)g,
        (__attribute__((address_space(3))) unsigned int*)l, 16, 0, 0);
}

// ---------------- e_sq[v] = sum_c emb[v][c]^2 ----------------
__global__ void esq_kernel(const float* __restrict__ emb,
                           float* __restrict__ esq) {
    int v    = blockIdx.x * 4 + (threadIdx.x >> 6);
    int lane = threadIdx.x & 63;
    float2 e = *(const float2*)(emb + (size_t)v * CDIM + lane * 2);
    float s = e.x * e.x + e.y * e.y;
    #pragma unroll
    for (int d = 32; d; d >>= 1) s += __shfl_xor(s, d, 64);
    if (lane == 0) esq[v] = s;
}

// ---------------- pack f32 [nrows][128] -> MFMA fragment layout ----------------
// Fragment (rb, c, s): 64 lanes x 8 bf16, element: src[rb*32 + (l&31)][c*16 + (l>>5)*8 + e]
// dst offset (ushort): ((rb*8 + c)*2 + s)*512 + l*8.  scale applied before split.
// Also inits this block's 32 keys (replaces hipMemsetAsync).
__global__ __launch_bounds__(256) void pack_kernel(const float* __restrict__ src,
        ushort_t* __restrict__ dst, u64* __restrict__ keys, int nrows, float scale) {
    __shared__ float sm[32][129];
    int rb = blockIdx.x, t = threadIdx.x;
    if (t < 32) keys[rb * 32 + t] = ~0ull;
    int rl = t >> 3, d0 = (t & 7) * 16;
    int row = rb * 32 + rl;
    if (row > nrows - 1) row = nrows - 1;
    const float4* s4 = (const float4*)(src + (size_t)row * CDIM + d0);
    #pragma unroll
    for (int j = 0; j < 4; j++) {
        float4 v = s4[j];
        sm[rl][d0 + 4*j + 0] = v.x; sm[rl][d0 + 4*j + 1] = v.y;
        sm[rl][d0 + 4*j + 2] = v.z; sm[rl][d0 + 4*j + 3] = v.w;
    }
    __syncthreads();
    #pragma unroll
    for (int k = 0; k < 2; k++) {
        int s = t + 256 * k;
        int c = s >> 6, l = s & 63;
        int r = l & 31, dbase = c * 16 + (l >> 5) * 8;
        bf16x8 vh, vl;
        #pragma unroll
        for (int e = 0; e < 8; e++) {
            float x = sm[r][dbase + e] * scale;
            ushort_t hh = f2bf(x);
            vh[e] = (short)hh;
            vl[e] = (short)f2bf(x - bf2f(hh));
        }
        size_t base = ((size_t)(rb * 8 + c) * 2) * 512 + (size_t)l * 8;
        *(bf16x8*)(dst + base)       = vh;
        *(bf16x8*)(dst + base + 512) = vl;
    }
}

// ---------------- emb pack (no keys init) ----------------
__global__ __launch_bounds__(256) void pack_emb_kernel(const float* __restrict__ src,
        ushort_t* __restrict__ dst) {
    __shared__ float sm[32][129];
    int rb = blockIdx.x, t = threadIdx.x;
    int rl = t >> 3, d0 = (t & 7) * 16;
    const float4* s4 = (const float4*)(src + (size_t)(rb * 32 + rl) * CDIM + d0);
    #pragma unroll
    for (int j = 0; j < 4; j++) {
        float4 v = s4[j];
        sm[rl][d0 + 4*j + 0] = v.x; sm[rl][d0 + 4*j + 1] = v.y;
        sm[rl][d0 + 4*j + 2] = v.z; sm[rl][d0 + 4*j + 3] = v.w;
    }
    __syncthreads();
    #pragma unroll
    for (int k = 0; k < 2; k++) {
        int s = t + 256 * k;
        int c = s >> 6, l = s & 63;
        int r = l & 31, dbase = c * 16 + (l >> 5) * 8;
        bf16x8 vh, vl;
        #pragma unroll
        for (int e = 0; e < 8; e++) {
            float x = sm[r][dbase + e];
            ushort_t hh = f2bf(x);
            vh[e] = (short)hh;
            vl[e] = (short)f2bf(x - bf2f(hh));
        }
        size_t base = ((size_t)(rb * 8 + c) * 2) * 512 + (size_t)l * 8;
        *(bf16x8*)(dst + base)       = vh;
        *(bf16x8*)(dst + base + 512) = vl;
    }
}

// ---------------- L5 pack: rows=(b,h,w) straight from [B][C][H][W], scale=-2 ----------------
__global__ __launch_bounds__(256) void pack_l5_kernel(const float* __restrict__ src,
        ushort_t* __restrict__ dst, u64* __restrict__ keys) {
    __shared__ float sm[128][36];
    int bh = blockIdx.x;            // rb == bh
    int b = bh >> 5, h = bh & 31;
    int t = threadIdx.x;
    if (t < 32) keys[bh * 32 + t] = ~0ull;
    int d = t >> 1, w0 = (t & 1) * 16;
    const float* sp = src + (((size_t)b * CDIM + d) * 32 + h) * 32 + w0;
    #pragma unroll
    for (int j = 0; j < 16; j++) sm[d][w0 + j] = sp[j];
    __syncthreads();
    #pragma unroll
    for (int k = 0; k < 2; k++) {
        int s = t + 256 * k;
        int c = s >> 6, l = s & 63;
        int w = l & 31, dbase = c * 16 + (l >> 5) * 8;
        bf16x8 vh, vl;
        #pragma unroll
        for (int e = 0; e < 8; e++) {
            float x = sm[dbase + e][w] * -2.0f;
            ushort_t hh = f2bf(x);
            vh[e] = (short)hh;
            vl[e] = (short)f2bf(x - bf2f(hh));
        }
        size_t base = ((size_t)(bh * 8 + c) * 2) * 512 + (size_t)l * 8;
        *(bf16x8*)(dst + base)       = vh;
        *(bf16x8*)(dst + base + 512) = vl;
    }
}

// ---------------- wave-parallel area downsample -> zd_f32[row][dim] ----------------
__global__ __launch_bounds__(256) void down_kernel(const float* __restrict__ src,
        float* __restrict__ zd, int lf /*log2 f*/) {
    int f  = 1 << lf;
    int ff = f * f;
    int llpi = (2 * lf > 6) ? 6 : 2 * lf;
    int lpi  = 1 << llpi;
    int epl  = ff >> llpi;
    int t    = blockIdx.x * 256 + threadIdx.x;
    int item = t >> llpi;
    int wi   = t & (lpi - 1);
    int row = item >> 7, dim = item & 127;
    int lpn = 5 - lf;
    int b  = row >> (2 * lpn);
    int rem = row & ((1 << (2 * lpn)) - 1);
    int ph = rem >> lpn, pw = rem & ((1 << lpn) - 1);
    const float* sp = src + (((size_t)b * CDIM + dim) * 32 + (ph << lf)) * 32 + (pw << lf);
    float s = 0.f;
    for (int k = 0; k < epl; k++) {
        int flat = wi * epl + k;
        int u = flat >> lf, v = flat & (f - 1);
        s += sp[u * 32 + v];
    }
    for (int d = lpi >> 1; d; d >>= 1) s += __shfl_xor(s, d, 64);
    if (wi == 0) zd[(size_t)row * CDIM + dim] = s * (1.0f / (float)ff);
}

// ---------------- MFMA argmin: 8 waves x 64 rows = 512 rows/block ----------------
// 3 x 16KB LDS ring + 2KB esq = 50KB total -> 2 blocks/CU co-reside
// (R8: 68KB pinned occupancy at 1 block/CU). Pipeline depth 2: stage t+2
// after barrier; vmcnt(2) steady state, vmcnt(0) only on the last step.
__global__ __launch_bounds__(512) void argmin_kernel(
        const ushort_t* __restrict__ apk, const ushort_t* __restrict__ bpk,
        const float* __restrict__ esq, u64* __restrict__ keys,
        int tiles, int cps) {
    __shared__ ushort_t lds[3][8192];   // 3 x 16 KB ring
    __shared__ float es_lds[512];

    int bid = blockIdx.x;
    // XCD swizzle: same-XCD blocks share a B-slice (slices % 8 == 0 always)
    int q     = bid >> 3;
    int tile  = q % tiles;
    int slice = (bid & 7) + 8 * (q / tiles);
    int code0 = slice * cps;
    int steps = cps >> 5;
    int tid = threadIdx.x, wv = tid >> 6, l = tid & 63, l31 = l & 31, lh = l >> 5;

    // A fragments: 2 row-tiles of 32 rows each (64 VMEM loads)
    int rb0 = tile * 16 + wv * 2;
    const ushort_t* ap = apk + (size_t)rb0 * 8192 + l * 8;
    bf16x8 a0h[8], a0l[8], a1h[8], a1l[8];
    #pragma unroll
    for (int c = 0; c < 8; c++) {
        a0h[c] = *(const bf16x8*)(ap + (2 * c) * 512);
        a0l[c] = *(const bf16x8*)(ap + (2 * c + 1) * 512);
        a1h[c] = *(const bf16x8*)(ap + 8192 + (2 * c) * 512);
        a1l[c] = *(const bf16x8*)(ap + 8192 + (2 * c + 1) * 512);
    }
    float ev0 = esq[code0 + (tid & (cps - 1))];
    __builtin_amdgcn_sched_barrier(0);   // pin: A+esq issue before staging

    const char* bbase = (const char*)bpk + (size_t)(code0 >> 5) * 16384;
    int issue = wv * 2;                  // this wave's 2 x 1KB staging chunks
    {   // prologue: stage steps 0..1
        const char* g0 = bbase + (size_t)issue * 1024 + (size_t)l * 16;
        gload_lds16(g0, &lds[0][issue * 512]);
        gload_lds16(g0 + 1024, &lds[0][issue * 512 + 512]);
        if (steps > 1) {
            gload_lds16(g0 + 16384, &lds[1][issue * 512]);
            gload_lds16(g0 + 17408, &lds[1][issue * 512 + 512]);
        }
    }
    __builtin_amdgcn_sched_barrier(0);
    if (tid < cps) es_lds[tid] = ev0;    // compiler inserts vmcnt covering ev0 (+A)
    asm volatile("s_waitcnt lgkmcnt(0)" ::: "memory");

    float best[32];
    int   bidx[32];
    #pragma unroll
    for (int r = 0; r < 32; r++) { best[r] = 1e38f; bidx[r] = 0; }

    int cur = 0;
    for (int t = 0; t < steps; ++t) {
        if (t + 1 < steps) asm volatile("s_waitcnt vmcnt(2)" ::: "memory");
        else               asm volatile("s_waitcnt vmcnt(0)" ::: "memory");
        __builtin_amdgcn_s_barrier();    // all waves: buf[cur] staged & prev consumed
        if (t + 2 < steps) {             // refill ring AFTER barrier (reuse-safe)
            const char* g = bbase + (size_t)(t + 2) * 16384
                          + (size_t)issue * 1024 + (size_t)l * 16;
            int nxt = cur + 2; if (nxt >= 3) nxt -= 3;
            ushort_t* d = &lds[nxt][issue * 512];
            gload_lds16(g, d);
            gload_lds16(g + 1024, d + 512);
        }
        float es = es_lds[(t << 5) + l31];
        f32x16 acc0, acc1;
        #pragma unroll
        for (int r = 0; r < 16; r++) { acc0[r] = es; acc1[r] = es; }
        const ushort_t* lp = &lds[cur][0] + l * 8;
        __builtin_amdgcn_s_setprio(1);
        #pragma unroll
        for (int c = 0; c < 8; c++) {
            bf16x8 vh = *(const bf16x8*)(lp + (2 * c) * 512);
            bf16x8 vl = *(const bf16x8*)(lp + (2 * c + 1) * 512);
            acc0 = __builtin_amdgcn_mfma_f32_32x32x16_bf16(a0h[c], vh, acc0, 0, 0, 0);
            acc1 = __builtin_amdgcn_mfma_f32_32x32x16_bf16(a1h[c], vh, acc1, 0, 0, 0);
            acc0 = __builtin_amdgcn_mfma_f32_32x32x16_bf16(a0h[c], vl, acc0, 0, 0, 0);
            acc1 = __builtin_amdgcn_mfma_f32_32x32x16_bf16(a1h[c], vl, acc1, 0, 0, 0);
            acc0 = __builtin_amdgcn_mfma_f32_32x32x16_bf16(a0l[c], vh, acc0, 0, 0, 0);
            acc1 = __builtin_amdgcn_mfma_f32_32x32x16_bf16(a1l[c], vh, acc1, 0, 0, 0);
        }
        __builtin_amdgcn_s_setprio(0);
        int code = code0 + (t << 5) + l31;
        #pragma unroll
        for (int r = 0; r < 16; r++) {
            float s0 = acc0[r];
            bool lt0 = s0 < best[r];
            best[r] = lt0 ? s0 : best[r];
            bidx[r] = lt0 ? code : bidx[r];
            float s1 = acc1[r];
            bool lt1 = s1 < best[16 + r];
            best[16 + r] = lt1 ? s1 : best[16 + r];
            bidx[16 + r] = lt1 ? code : bidx[16 + r];
        }
        cur = (cur + 1 == 3) ? 0 : cur + 1;
    }

    #pragma unroll
    for (int rt = 0; rt < 2; rt++) {
        #pragma unroll
        for (int r = 0; r < 16; r++) {
            u32 fb = __float_as_uint(best[rt * 16 + r]);
            fb = (fb & 0x80000000u) ? ~fb : (fb | 0x80000000u);
            u64 key = ((u64)fb << 32) | (u32)bidx[rt * 16 + r];
            #pragma unroll
            for (int d = 1; d < 32; d <<= 1) {
                u64 o = __shfl_xor(key, d, 64);
                key = (o < key) ? o : key;
            }
            if (l31 == 0) {
                int rw = tile * 512 + wv * 64 + rt * 32
                       + (r & 3) + 8 * (r >> 2) + 4 * lh;
                atomicMin(&keys[rw], key);
            }
        }
    }
}

// ---------------- bicubic weight (a = -0.75) ----------------
__device__ __forceinline__ float cubicw(float t) {
    float t2 = t * t;
    if (t <= 1.0f) return (1.25f * t - 2.25f) * t2 + 1.0f;
    return -0.75f * (((t - 5.0f) * t + 8.0f) * t - 4.0f);
}

// ---------------- upsample + residual update + output (float4 over w) ----------------
__global__ __launch_bounds__(256) void up_kernel(
        const float* __restrict__ emb,
        const u64* __restrict__ keys,
        const float* __restrict__ src,   // z_enc (lvl0) or zrest
        const float* __restrict__ prev,  // out[lvl-1] (unused if first)
        float* __restrict__ zrest,
        float* __restrict__ out,
        int pn, int last, int first) {
    __shared__ float wtab[32][4];
    __shared__ int   itab[32][4];
    int tid = threadIdx.x;
    if (!last && tid < 128) {
        int pos = tid >> 2, tap = tid & 3;
        float s  = (float)pn * (1.0f / 32.0f);
        float x  = ((float)pos + 0.5f) * s - 0.5f;
        float x0 = floorf(x);
        float t  = x - x0;
        int   off = tap - 1;
        float w  = cubicw(fabsf((float)off - t));
        int   jj = (int)x0 + off;
        jj = min(max(jj, 0), pn - 1);
        wtab[pos][tap] = w;
        itab[pos][tap] = jj;
    }
    __syncthreads();

    int t  = blockIdx.x * 256 + tid;
    int w4 = (t & 7) << 2;
    int h  = (t >> 3) & 31;
    int c  = (t >> 8) & 127;
    int b  = t >> 15;
    size_t i = (((size_t)b * CDIM + c) * 32 + h) * 32 + w4;

    float zu[4];
    if (last) {
        int kb = (b << 10) + (h << 5) + w4;
        #pragma unroll
        for (int j = 0; j < 4; j++) {
            int tok = (int)(keys[kb + j] & 0xFFFFFFFFull);
            zu[j] = emb[(size_t)tok * CDIM + c];
        }
    } else {
        int base = b * pn * pn;
        #pragma unroll
        for (int j = 0; j < 4; j++) zu[j] = 0.f;
        #pragma unroll
        for (int u = 0; u < 4; u++) {
            float whu = wtab[h][u];
            int   ih  = itab[h][u] * pn;
            #pragma unroll
            for (int j = 0; j < 4; j++) {
                float acc = 0.f;
                #pragma unroll
                for (int v = 0; v < 4; v++) {
                    int tok = (int)(keys[base + ih + itab[w4 + j][v]] & 0xFFFFFFFFull);
                    acc += wtab[w4 + j][v] * emb[(size_t)tok * CDIM + c];
                }
                zu[j] += whu * acc;
            }
        }
    }
    float4 sv = *(const float4*)(src + i);
    float4 pv = {0.f, 0.f, 0.f, 0.f};
    if (!first) pv = *(const float4*)(prev + i);
    float4 ov, rv;
    ov.x = pv.x + zu[0]; ov.y = pv.y + zu[1]; ov.z = pv.z + zu[2]; ov.w = pv.w + zu[3];
    rv.x = sv.x - zu[0]; rv.y = sv.y - zu[1]; rv.z = sv.z - zu[2]; rv.w = sv.w - zu[3];
    *(float4*)(out + i)   = ov;
    *(float4*)(zrest + i) = rv;
}

extern "C" void kernel_launch(void* const* d_in, const int* in_sizes, int n_in,
                              void* d_out, int out_size, void* d_ws, size_t ws_size,
                              hipStream_t stream) {
    const float* z_enc = (const float*)d_in[0];
    const float* emb   = (const float*)d_in[1];
    float* out = (float*)d_out;
    float* ws  = (float*)d_ws;

    // ws layout (float offsets)
    float*    zrest  = ws;                                // 2,097,152
    float*    zd_f32 = ws + 2097152;                      // 2,097,152
    ushort_t* zd_pk  = (ushort_t*)(ws + 4194304);         // 4,194,304 ushort
    ushort_t* emb_pk = (ushort_t*)(ws + 6291456);         // 2,097,152 ushort
    float*    esq    = ws + 7340032;                      // 8192
    u64*      keys   = (u64*)(ws + 7348224);              // 16384 u64

    esq_kernel<<<NCODES / 4, 256, 0, stream>>>(emb, esq);
    pack_emb_kernel<<<NCODES / 32, 256, 0, stream>>>(emb, emb_pk);

    const int MS_[6] = {1, 2, 4, 8, 16, 32};
    const int SL_[6] = {256, 256, 256, 256, 64, 16};
    for (int lvl = 0; lvl < 6; lvl++) {
        int pn     = MS_[lvl];
        int lf     = 5 - lvl;               // log2(32/pn)
        int rows   = 16 * pn * pn;
        int tiles  = (rows + 511) / 512;
        int slices = SL_[lvl];
        int cps    = NCODES / slices;
        const float* src = lvl ? zrest : z_enc;

        if (lvl < 5) {
            int ff  = 1 << (2 * lf);
            int lpi = ff < 64 ? ff : 64;
            down_kernel<<<rows * 128 * lpi / 256, 256, 0, stream>>>(src, zd_f32, lf);
            pack_kernel<<<tiles * 16, 256, 0, stream>>>(zd_f32, zd_pk, keys, rows, -2.0f);
        } else {
            pack_l5_kernel<<<512, 256, 0, stream>>>(src, zd_pk, keys);
        }
        argmin_kernel<<<tiles * slices, 512, 0, stream>>>(
            zd_pk, emb_pk, esq, keys, tiles, cps);
        up_kernel<<<NTOT / 4 / 256, 256, 0, stream>>>(
            emb, keys, src, lvl ? (out + (size_t)(lvl - 1) * NTOT) : out,
            zrest, out + (size_t)lvl * NTOT, pn, lvl == 5 ? 1 : 0, lvl == 0 ? 1 : 0);
    }
}

// Round 10
// 505.503 us; speedup vs baseline: 1.0982x; 1.0982x over previous
//
#include <hip/hip_runtime.h>
#include <hip/hip_bf16.h>

#define NCODES 8192
#define CDIM 128
#define NTOT (16*128*32*32)   // 2097152

typedef __attribute__((ext_vector_type(8))) short bf16x8;
typedef __attribute__((ext_vector_type(16))) float f32x16;
typedef unsigned long long u64;
typedef unsigned int u32;
typedef unsigned short ushort_t;

__device__ __forceinline__ ushort_t f2bf(float x) {
    u32 u = __float_as_uint(x);
    u32 r = (u + 0x7FFFu + ((u >> 16) & 1u)) >> 16;
    return (ushort_t)r;
}
__device__ __forceinline__ float bf2f(ushort_t h) {
    return __uint_as_float(((u32)h) << 16);
}

__device__ __forceinline__ void gload_lds16(const void* g, void* l) {
    __builtin_amdgcn_global_load_lds(
        (const __attribute__((address_space(1))) unsigned int*)g,
        (__attribute__((address_space(3))) unsigned int*)l, 16, 0, 0);
}

// ---------------- emb pack + esq (fused) ----------------
// Fragment (rb, c, s): 64 lanes x 8 bf16, element: src[rb*32 + (l&31)][c*16 + (l>>5)*8 + e]
__global__ __launch_bounds__(256) void pack_emb_kernel(const float* __restrict__ src,
        ushort_t* __restrict__ dst, float* __restrict__ esq) {
    __shared__ float sm[32][129];
    int rb = blockIdx.x, t = threadIdx.x;
    int rl = t >> 3, d0 = (t & 7) * 16;
    const float4* s4 = (const float4*)(src + (size_t)(rb * 32 + rl) * CDIM + d0);
    #pragma unroll
    for (int j = 0; j < 4; j++) {
        float4 v = s4[j];
        sm[rl][d0 + 4*j + 0] = v.x; sm[rl][d0 + 4*j + 1] = v.y;
        sm[rl][d0 + 4*j + 2] = v.z; sm[rl][d0 + 4*j + 3] = v.w;
    }
    __syncthreads();
    {   // esq: 8 threads per code row, 16 dims each, 8-lane shfl reduce
        int r = t >> 3, g = t & 7;
        float s = 0.f;
        #pragma unroll
        for (int k = 0; k < 16; k++) { float x = sm[r][g * 16 + k]; s += x * x; }
        s += __shfl_xor(s, 1, 64);
        s += __shfl_xor(s, 2, 64);
        s += __shfl_xor(s, 4, 64);
        if (g == 0) esq[rb * 32 + r] = s;
    }
    #pragma unroll
    for (int k = 0; k < 2; k++) {
        int s = t + 256 * k;
        int c = s >> 6, l = s & 63;
        int r = l & 31, dbase = c * 16 + (l >> 5) * 8;
        bf16x8 vh, vl;
        #pragma unroll
        for (int e = 0; e < 8; e++) {
            float x = sm[r][dbase + e];
            ushort_t hh = f2bf(x);
            vh[e] = (short)hh;
            vl[e] = (short)f2bf(x - bf2f(hh));
        }
        size_t base = ((size_t)(rb * 8 + c) * 2) * 512 + (size_t)l * 8;
        *(bf16x8*)(dst + base)       = vh;
        *(bf16x8*)(dst + base + 512) = vl;
    }
}

// ---------------- pack f32 [nrows][128] -> fragment layout (+keys init) ----------------
__global__ __launch_bounds__(256) void pack_kernel(const float* __restrict__ src,
        ushort_t* __restrict__ dst, u64* __restrict__ keys, int nrows, float scale) {
    __shared__ float sm[32][129];
    int rb = blockIdx.x, t = threadIdx.x;
    if (t < 32) keys[rb * 32 + t] = ~0ull;
    int rl = t >> 3, d0 = (t & 7) * 16;
    int row = rb * 32 + rl;
    if (row > nrows - 1) row = nrows - 1;
    const float4* s4 = (const float4*)(src + (size_t)row * CDIM + d0);
    #pragma unroll
    for (int j = 0; j < 4; j++) {
        float4 v = s4[j];
        sm[rl][d0 + 4*j + 0] = v.x; sm[rl][d0 + 4*j + 1] = v.y;
        sm[rl][d0 + 4*j + 2] = v.z; sm[rl][d0 + 4*j + 3] = v.w;
    }
    __syncthreads();
    #pragma unroll
    for (int k = 0; k < 2; k++) {
        int s = t + 256 * k;
        int c = s >> 6, l = s & 63;
        int r = l & 31, dbase = c * 16 + (l >> 5) * 8;
        bf16x8 vh, vl;
        #pragma unroll
        for (int e = 0; e < 8; e++) {
            float x = sm[r][dbase + e] * scale;
            ushort_t hh = f2bf(x);
            vh[e] = (short)hh;
            vl[e] = (short)f2bf(x - bf2f(hh));
        }
        size_t base = ((size_t)(rb * 8 + c) * 2) * 512 + (size_t)l * 8;
        *(bf16x8*)(dst + base)       = vh;
        *(bf16x8*)(dst + base + 512) = vl;
    }
}

// ---------------- L5 pack: rows=(b,h,w) from [B][C][H][W], scale=-2 (+keys init) -----
__global__ __launch_bounds__(256) void pack_l5_kernel(const float* __restrict__ src,
        ushort_t* __restrict__ dst, u64* __restrict__ keys) {
    __shared__ float sm[128][36];
    int bh = blockIdx.x;            // rb == bh
    int b = bh >> 5, h = bh & 31;
    int t = threadIdx.x;
    if (t < 32) keys[bh * 32 + t] = ~0ull;
    int d = t >> 1, w0 = (t & 1) * 16;
    const float* sp = src + (((size_t)b * CDIM + d) * 32 + h) * 32 + w0;
    #pragma unroll
    for (int j = 0; j < 16; j++) sm[d][w0 + j] = sp[j];
    __syncthreads();
    #pragma unroll
    for (int k = 0; k < 2; k++) {
        int s = t + 256 * k;
        int c = s >> 6, l = s & 63;
        int w = l & 31, dbase = c * 16 + (l >> 5) * 8;
        bf16x8 vh, vl;
        #pragma unroll
        for (int e = 0; e < 8; e++) {
            float x = sm[dbase + e][w] * -2.0f;
            ushort_t hh = f2bf(x);
            vh[e] = (short)hh;
            vl[e] = (short)f2bf(x - bf2f(hh));
        }
        size_t base = ((size_t)(bh * 8 + c) * 2) * 512 + (size_t)l * 8;
        *(bf16x8*)(dst + base)       = vh;
        *(bf16x8*)(dst + base + 512) = vl;
    }
}

// ---------------- level-0 initial area downsample (z_enc -> zd_f32) ----------------
__global__ __launch_bounds__(256) void down_kernel(const float* __restrict__ src,
        float* __restrict__ zd, int lf /*log2 f*/) {
    int f  = 1 << lf;
    int ff = f * f;
    int llpi = (2 * lf > 6) ? 6 : 2 * lf;
    int lpi  = 1 << llpi;
    int epl  = ff >> llpi;
    int t    = blockIdx.x * 256 + threadIdx.x;
    int item = t >> llpi;
    int wi   = t & (lpi - 1);
    int row = item >> 7, dim = item & 127;
    int lpn = 5 - lf;
    int b  = row >> (2 * lpn);
    int rem = row & ((1 << (2 * lpn)) - 1);
    int ph = rem >> lpn, pw = rem & ((1 << lpn) - 1);
    const float* sp = src + (((size_t)b * CDIM + dim) * 32 + (ph << lf)) * 32 + (pw << lf);
    float s = 0.f;
    for (int k = 0; k < epl; k++) {
        int flat = wi * epl + k;
        int u = flat >> lf, v = flat & (f - 1);
        s += sp[u * 32 + v];
    }
    for (int d = lpi >> 1; d; d >>= 1) s += __shfl_xor(s, d, 64);
    if (wi == 0) zd[(size_t)row * CDIM + dim] = s * (1.0f / (float)ff);
}

// ---------------- MFMA argmin: 8 waves x 32 rows = 256 rows/block ----------------
// Three INDEPENDENT accumulator chains (hh/hl/lh, each 8 MFMAs deep per step)
// + explicit 1-chunk ds_read rotation (issue c+1 before c's MFMAs) to break
// the per-chunk read->wait->use serialization that pinned MfmaUtil at ~35%.
// 3 x 16KB LDS ring, counted vmcnt (2 staging loads/wave/step in loop).
__global__ __launch_bounds__(512) void argmin_kernel(
        const ushort_t* __restrict__ apk, const ushort_t* __restrict__ bpk,
        const float* __restrict__ esq, u64* __restrict__ keys,
        int tiles, int cps) {
    __shared__ ushort_t lds[3][8192];   // 3 x 16 KB ring
    __shared__ float es_lds[1024];

    int bid = blockIdx.x;
    // XCD swizzle: same-XCD blocks share a B-slice (tiles*slices % 8 == 0 always)
    int q     = bid >> 3;
    int tile  = q % tiles;
    int slice = (bid & 7) + 8 * (q / tiles);
    int code0 = slice * cps;
    int steps = cps >> 5;
    int tid = threadIdx.x, wv = tid >> 6, l = tid & 63, l31 = l & 31, lh = l >> 5;

    // A fragments: one 32-row tile per wave (32 VMEM loads, 64 VGPR)
    int rb = tile * 8 + wv;
    const ushort_t* ap = apk + (size_t)rb * 8192 + l * 8;
    bf16x8 a_h[8], a_l[8];
    #pragma unroll
    for (int c = 0; c < 8; c++) {
        a_h[c] = *(const bf16x8*)(ap + (2 * c) * 512);
        a_l[c] = *(const bf16x8*)(ap + (2 * c + 1) * 512);
    }
    float ev0 = esq[code0 + (tid & (cps - 1))];
    float ev1 = esq[code0 + ((tid + 512) & (cps - 1))];
    __builtin_amdgcn_sched_barrier(0);   // pin: A+esq issue before staging

    const char* bbase = (const char*)bpk + (size_t)(code0 >> 5) * 16384;
    int issue = wv * 2;                  // this wave's 2 x 1KB staging chunks
    {   // prologue: stage steps 0..1
        const char* g0 = bbase + (size_t)issue * 1024 + (size_t)l * 16;
        gload_lds16(g0, &lds[0][issue * 512]);
        gload_lds16(g0 + 1024, &lds[0][issue * 512 + 512]);
        if (steps > 1) {
            gload_lds16(g0 + 16384, &lds[1][issue * 512]);
            gload_lds16(g0 + 17408, &lds[1][issue * 512 + 512]);
        }
    }
    __builtin_amdgcn_sched_barrier(0);
    es_lds[tid] = ev0;                   // compiler inserts vmcnt covering ev0/ev1 (+A)
    es_lds[tid + 512] = ev1;
    asm volatile("s_waitcnt lgkmcnt(0)" ::: "memory");

    float best[16];
    int   bidx[16];
    #pragma unroll
    for (int r = 0; r < 16; r++) { best[r] = 1e38f; bidx[r] = 0; }

    int cur = 0;
    for (int t = 0; t < steps; ++t) {
        if (t + 1 < steps) asm volatile("s_waitcnt vmcnt(2)" ::: "memory");
        else               asm volatile("s_waitcnt vmcnt(0)" ::: "memory");
        __builtin_amdgcn_s_barrier();    // all waves: buf[cur] staged & prev consumed
        if (t + 2 < steps) {             // refill ring AFTER barrier (reuse-safe)
            const char* g = bbase + (size_t)(t + 2) * 16384
                          + (size_t)issue * 1024 + (size_t)l * 16;
            int nxt = cur + 2; if (nxt >= 3) nxt -= 3;
            ushort_t* d = &lds[nxt][issue * 512];
            gload_lds16(g, d);
            gload_lds16(g + 1024, d + 512);
        }
        float es = es_lds[(t << 5) + l31];
        f32x16 ahh, ahl, alh;
        #pragma unroll
        for (int r = 0; r < 16; r++) { ahh[r] = es; ahl[r] = 0.f; alh[r] = 0.f; }
        const ushort_t* lp = &lds[cur][0] + l * 8;
        bf16x8 vh = *(const bf16x8*)(lp);
        bf16x8 vl = *(const bf16x8*)(lp + 512);
        __builtin_amdgcn_s_setprio(1);
        #pragma unroll
        for (int c = 0; c < 8; c++) {
            bf16x8 nvh = vh, nvl = vl;
            if (c < 7) {                 // read-ahead: issue c+1 before c's MFMAs
                nvh = *(const bf16x8*)(lp + (2 * c + 2) * 512);
                nvl = *(const bf16x8*)(lp + (2 * c + 3) * 512);
            }
            ahh = __builtin_amdgcn_mfma_f32_32x32x16_bf16(a_h[c], vh, ahh, 0, 0, 0);
            ahl = __builtin_amdgcn_mfma_f32_32x32x16_bf16(a_h[c], vl, ahl, 0, 0, 0);
            alh = __builtin_amdgcn_mfma_f32_32x32x16_bf16(a_l[c], vh, alh, 0, 0, 0);
            vh = nvh; vl = nvl;
        }
        __builtin_amdgcn_s_setprio(0);
        int code = code0 + (t << 5) + l31;
        #pragma unroll
        for (int r = 0; r < 16; r++) {
            float s = (ahh[r] + ahl[r]) + alh[r];
            bool lt = s < best[r];
            best[r] = lt ? s : best[r];
            bidx[r] = lt ? code : bidx[r];
        }
        cur = (cur + 1 == 3) ? 0 : cur + 1;
    }

    #pragma unroll
    for (int r = 0; r < 16; r++) {
        u32 fb = __float_as_uint(best[r]);
        fb = (fb & 0x80000000u) ? ~fb : (fb | 0x80000000u);
        u64 key = ((u64)fb << 32) | (u32)bidx[r];
        #pragma unroll
        for (int d = 1; d < 32; d <<= 1) {
            u64 o = __shfl_xor(key, d, 64);
            key = (o < key) ? o : key;
        }
        if (l31 == 0) {
            int rw = tile * 256 + wv * 32 + (r & 3) + 8 * (r >> 2) + 4 * lh;
            atomicMin(&keys[rw], key);
        }
    }
}

// ---------------- bicubic weight (a = -0.75) ----------------
__device__ __forceinline__ float cubicw(float t) {
    float t2 = t * t;
    if (t <= 1.0f) return (1.25f * t - 2.25f) * t2 + 1.0f;
    return -0.75f * (((t - 5.0f) * t + 8.0f) * t - 4.0f);
}

// ---------------- upsample + residual update + output + FUSED downsample ----------
// Block = one (b,c) spatial plane. After computing the residual rv, per-thread
// register partials feed a tiny LDS tree that emits next level's zd_f32 rows.
__global__ __launch_bounds__(256) void up_kernel(
        const float* __restrict__ emb,
        const u64* __restrict__ keys,
        const float* __restrict__ src,   // z_enc (lvl0) or zrest
        const float* __restrict__ prev,  // out[lvl-1] (unused if first)
        float* __restrict__ zrest,
        float* __restrict__ out,
        float* __restrict__ zd_next,     // next level's zd (if pnn > 0)
        int pn, int last, int first, int pnn) {
    __shared__ float wtab[32][4];
    __shared__ int   itab[32][4];
    __shared__ float smp[512];
    int tid = threadIdx.x;
    if (!last && tid < 128) {
        int pos = tid >> 2, tap = tid & 3;
        float s  = (float)pn * (1.0f / 32.0f);
        float x  = ((float)pos + 0.5f) * s - 0.5f;
        float x0 = floorf(x);
        float t  = x - x0;
        int   off = tap - 1;
        float w  = cubicw(fabsf((float)off - t));
        int   jj = (int)x0 + off;
        jj = min(max(jj, 0), pn - 1);
        wtab[pos][tap] = w;
        itab[pos][tap] = jj;
    }
    __syncthreads();

    int t  = blockIdx.x * 256 + tid;
    int w4 = (t & 7) << 2;
    int h  = (t >> 3) & 31;
    int c  = (t >> 8) & 127;
    int b  = t >> 15;
    size_t i = (((size_t)b * CDIM + c) * 32 + h) * 32 + w4;

    float zu[4];
    if (last) {
        int kb = (b << 10) + (h << 5) + w4;
        #pragma unroll
        for (int j = 0; j < 4; j++) {
            int tok = (int)(keys[kb + j] & 0xFFFFFFFFull);
            zu[j] = emb[(size_t)tok * CDIM + c];
        }
    } else {
        int base = b * pn * pn;
        #pragma unroll
        for (int j = 0; j < 4; j++) zu[j] = 0.f;
        #pragma unroll
        for (int u = 0; u < 4; u++) {
            float whu = wtab[h][u];
            int   ih  = itab[h][u] * pn;
            #pragma unroll
            for (int j = 0; j < 4; j++) {
                float acc = 0.f;
                #pragma unroll
                for (int v = 0; v < 4; v++) {
                    int tok = (int)(keys[base + ih + itab[w4 + j][v]] & 0xFFFFFFFFull);
                    acc += wtab[w4 + j][v] * emb[(size_t)tok * CDIM + c];
                }
                zu[j] += whu * acc;
            }
        }
    }
    float4 sv = *(const float4*)(src + i);
    float4 pv = {0.f, 0.f, 0.f, 0.f};
    if (!first) pv = *(const float4*)(prev + i);
    float4 ov, rv;
    ov.x = pv.x + zu[0]; ov.y = pv.y + zu[1]; ov.z = pv.z + zu[2]; ov.w = pv.w + zu[3];
    rv.x = sv.x - zu[0]; rv.y = sv.y - zu[1]; rv.z = sv.z - zu[2]; rv.w = sv.w - zu[3];
    *(float4*)(out + i)   = ov;
    *(float4*)(zrest + i) = rv;

    if (pnn) {   // fused area-downsample of rv for next level
        int f = 32 / pnn;
        if (f >= 4) {
            smp[h * 8 + (w4 >> 2)] = (rv.x + rv.y) + (rv.z + rv.w);
        } else {  // f == 2
            smp[h * 16 + (w4 >> 1)]     = rv.x + rv.y;
            smp[h * 16 + (w4 >> 1) + 1] = rv.z + rv.w;
        }
        __syncthreads();
        int W = pnn * pnn;
        if (tid < W) {
            int lb = __builtin_ctz(pnn);
            int ph = tid >> lb, pw = tid & (pnn - 1);
            float s = 0.f;
            if (f >= 4) {
                int cg = f >> 2;
                for (int u = 0; u < f; u++)
                    for (int v = 0; v < cg; v++)
                        s += smp[(ph * f + u) * 8 + pw * cg + v];
            } else {
                s = smp[(2 * ph) * 16 + pw] + smp[(2 * ph + 1) * 16 + pw];
            }
            int b2 = blockIdx.x >> 7, c2 = blockIdx.x & 127;
            int row = (b2 * pnn + ph) * pnn + pw;
            zd_next[(size_t)row * CDIM + c2] = s * (1.0f / (float)(f * f));
        }
    }
}

extern "C" void kernel_launch(void* const* d_in, const int* in_sizes, int n_in,
                              void* d_out, int out_size, void* d_ws, size_t ws_size,
                              hipStream_t stream) {
    const float* z_enc = (const float*)d_in[0];
    const float* emb   = (const float*)d_in[1];
    float* out = (float*)d_out;
    float* ws  = (float*)d_ws;

    // ws layout (float offsets)
    float*    zrest  = ws;                                // 2,097,152
    float*    zd_f32 = ws + 2097152;                      // 2,097,152
    ushort_t* zd_pk  = (ushort_t*)(ws + 4194304);         // 4,194,304 ushort
    ushort_t* emb_pk = (ushort_t*)(ws + 6291456);         // 2,097,152 ushort
    float*    esq    = ws + 7340032;                      // 8192
    u64*      keys   = (u64*)(ws + 7348224);              // 16384 u64

    pack_emb_kernel<<<NCODES / 32, 256, 0, stream>>>(emb, emb_pk, esq);
    down_kernel<<<512, 256, 0, stream>>>(z_enc, zd_f32, 5);   // level-0 prep

    const int MS_[6] = {1, 2, 4, 8, 16, 32};
    const int SL_[6] = {256, 256, 256, 64, 16, 8};
    for (int lvl = 0; lvl < 6; lvl++) {
        int pn     = MS_[lvl];
        int rows   = 16 * pn * pn;
        int tiles  = (rows + 255) / 256;
        int slices = SL_[lvl];
        int cps    = NCODES / slices;
        const float* src = lvl ? zrest : z_enc;

        if (lvl < 5) {
            pack_kernel<<<tiles * 8, 256, 0, stream>>>(zd_f32, zd_pk, keys, rows, -2.0f);
        } else {
            pack_l5_kernel<<<512, 256, 0, stream>>>(zrest, zd_pk, keys);
        }
        argmin_kernel<<<tiles * slices, 512, 0, stream>>>(
            zd_pk, emb_pk, esq, keys, tiles, cps);
        int pnn = (lvl < 4) ? MS_[lvl + 1] : 0;
        up_kernel<<<NTOT / 4 / 256, 256, 0, stream>>>(
            emb, keys, src, lvl ? (out + (size_t)(lvl - 1) * NTOT) : out,
            zrest, out + (size_t)lvl * NTOT, zd_f32,
            pn, lvl == 5 ? 1 : 0, lvl == 0 ? 1 : 0, pnn);
    }
}

// Round 11
// 436.459 us; speedup vs baseline: 1.2719x; 1.1582x over previous
//
#include <hip/hip_runtime.h>
#include <hip/hip_bf16.h>

#define NCODES 8192
#define CDIM 128
#define NTOT (16*128*32*32)   // 2097152

typedef __attribute__((ext_vector_type(8))) short bf16x8;
typedef __attribute__((ext_vector_type(16))) float f32x16;
typedef unsigned long long u64;
typedef unsigned int u32;
typedef unsigned short ushort_t;

__device__ __forceinline__ ushort_t f2bf(float x) {
    u32 u = __float_as_uint(x);
    u32 r = (u + 0x7FFFu + ((u >> 16) & 1u)) >> 16;
    return (ushort_t)r;
}
__device__ __forceinline__ float bf2f(ushort_t h) {
    return __uint_as_float(((u32)h) << 16);
}

__device__ __forceinline__ void gload_lds16(const void* g, void* l) {
    __builtin_amdgcn_global_load_lds(
        (const __attribute__((address_space(1))) unsigned int*)g,
        (__attribute__((address_space(3))) unsigned int*)l, 16, 0, 0);
}

// ---------------- emb pack + esq (fused) ----------------
// Fragment (rb, c, s): 64 lanes x 8 bf16, element: src[rb*32 + (l&31)][c*16 + (l>>5)*8 + e]
__global__ __launch_bounds__(256) void pack_emb_kernel(const float* __restrict__ src,
        ushort_t* __restrict__ dst, float* __restrict__ esq) {
    __shared__ float sm[32][129];
    int rb = blockIdx.x, t = threadIdx.x;
    int rl = t >> 3, d0 = (t & 7) * 16;
    const float4* s4 = (const float4*)(src + (size_t)(rb * 32 + rl) * CDIM + d0);
    #pragma unroll
    for (int j = 0; j < 4; j++) {
        float4 v = s4[j];
        sm[rl][d0 + 4*j + 0] = v.x; sm[rl][d0 + 4*j + 1] = v.y;
        sm[rl][d0 + 4*j + 2] = v.z; sm[rl][d0 + 4*j + 3] = v.w;
    }
    __syncthreads();
    {   // esq: 8 threads per code row, 16 dims each, 8-lane shfl reduce
        int r = t >> 3, g = t & 7;
        float s = 0.f;
        #pragma unroll
        for (int k = 0; k < 16; k++) { float x = sm[r][g * 16 + k]; s += x * x; }
        s += __shfl_xor(s, 1, 64);
        s += __shfl_xor(s, 2, 64);
        s += __shfl_xor(s, 4, 64);
        if (g == 0) esq[rb * 32 + r] = s;
    }
    #pragma unroll
    for (int k = 0; k < 2; k++) {
        int s = t + 256 * k;
        int c = s >> 6, l = s & 63;
        int r = l & 31, dbase = c * 16 + (l >> 5) * 8;
        bf16x8 vh, vl;
        #pragma unroll
        for (int e = 0; e < 8; e++) {
            float x = sm[r][dbase + e];
            ushort_t hh = f2bf(x);
            vh[e] = (short)hh;
            vl[e] = (short)f2bf(x - bf2f(hh));
        }
        size_t base = ((size_t)(rb * 8 + c) * 2) * 512 + (size_t)l * 8;
        *(bf16x8*)(dst + base)       = vh;
        *(bf16x8*)(dst + base + 512) = vl;
    }
}

// ---------------- pack f32 [nrows][128] -> fragment layout (+keys init) ----------------
__global__ __launch_bounds__(256) void pack_kernel(const float* __restrict__ src,
        ushort_t* __restrict__ dst, u64* __restrict__ keys, int nrows, float scale) {
    __shared__ float sm[32][129];
    int rb = blockIdx.x, t = threadIdx.x;
    if (t < 32) keys[rb * 32 + t] = ~0ull;
    int rl = t >> 3, d0 = (t & 7) * 16;
    int row = rb * 32 + rl;
    if (row > nrows - 1) row = nrows - 1;
    const float4* s4 = (const float4*)(src + (size_t)row * CDIM + d0);
    #pragma unroll
    for (int j = 0; j < 4; j++) {
        float4 v = s4[j];
        sm[rl][d0 + 4*j + 0] = v.x; sm[rl][d0 + 4*j + 1] = v.y;
        sm[rl][d0 + 4*j + 2] = v.z; sm[rl][d0 + 4*j + 3] = v.w;
    }
    __syncthreads();
    #pragma unroll
    for (int k = 0; k < 2; k++) {
        int s = t + 256 * k;
        int c = s >> 6, l = s & 63;
        int r = l & 31, dbase = c * 16 + (l >> 5) * 8;
        bf16x8 vh, vl;
        #pragma unroll
        for (int e = 0; e < 8; e++) {
            float x = sm[r][dbase + e] * scale;
            ushort_t hh = f2bf(x);
            vh[e] = (short)hh;
            vl[e] = (short)f2bf(x - bf2f(hh));
        }
        size_t base = ((size_t)(rb * 8 + c) * 2) * 512 + (size_t)l * 8;
        *(bf16x8*)(dst + base)       = vh;
        *(bf16x8*)(dst + base + 512) = vl;
    }
}

// ---------------- L5 pack: rows=(b,h,w) from [B][C][H][W], scale=-2 (+keys init) -----
__global__ __launch_bounds__(256) void pack_l5_kernel(const float* __restrict__ src,
        ushort_t* __restrict__ dst, u64* __restrict__ keys) {
    __shared__ float sm[128][36];
    int bh = blockIdx.x;            // rb == bh
    int b = bh >> 5, h = bh & 31;
    int t = threadIdx.x;
    if (t < 32) keys[bh * 32 + t] = ~0ull;
    int d = t >> 1, w0 = (t & 1) * 16;
    const float* sp = src + (((size_t)b * CDIM + d) * 32 + h) * 32 + w0;
    #pragma unroll
    for (int j = 0; j < 16; j++) sm[d][w0 + j] = sp[j];
    __syncthreads();
    #pragma unroll
    for (int k = 0; k < 2; k++) {
        int s = t + 256 * k;
        int c = s >> 6, l = s & 63;
        int w = l & 31, dbase = c * 16 + (l >> 5) * 8;
        bf16x8 vh, vl;
        #pragma unroll
        for (int e = 0; e < 8; e++) {
            float x = sm[dbase + e][w] * -2.0f;
            ushort_t hh = f2bf(x);
            vh[e] = (short)hh;
            vl[e] = (short)f2bf(x - bf2f(hh));
        }
        size_t base = ((size_t)(bh * 8 + c) * 2) * 512 + (size_t)l * 8;
        *(bf16x8*)(dst + base)       = vh;
        *(bf16x8*)(dst + base + 512) = vl;
    }
}

// ---------------- level-0 initial area downsample (z_enc -> zd_f32) ----------------
__global__ __launch_bounds__(256) void down_kernel(const float* __restrict__ src,
        float* __restrict__ zd, int lf /*log2 f*/) {
    int f  = 1 << lf;
    int ff = f * f;
    int llpi = (2 * lf > 6) ? 6 : 2 * lf;
    int lpi  = 1 << llpi;
    int epl  = ff >> llpi;
    int t    = blockIdx.x * 256 + threadIdx.x;
    int item = t >> llpi;
    int wi   = t & (lpi - 1);
    int row = item >> 7, dim = item & 127;
    int lpn = 5 - lf;
    int b  = row >> (2 * lpn);
    int rem = row & ((1 << (2 * lpn)) - 1);
    int ph = rem >> lpn, pw = rem & ((1 << lpn) - 1);
    const float* sp = src + (((size_t)b * CDIM + dim) * 32 + (ph << lf)) * 32 + (pw << lf);
    float s = 0.f;
    for (int k = 0; k < epl; k++) {
        int flat = wi * epl + k;
        int u = flat >> lf, v = flat & (f - 1);
        s += sp[u * 32 + v];
    }
    for (int d = lpi >> 1; d; d >>= 1) s += __shfl_xor(s, d, 64);
    if (wi == 0) zd[(size_t)row * CDIM + dim] = s * (1.0f / (float)ff);
}

// ---------------- MFMA argmin: 64 codes/step, 8 waves x 32 rows ----------------
// Fixed per-step overhead (~3k cyc: barrier skew, acc-init, epilogue VALU) was
// the measured wall (MfmaUtil pinned 31-40% across R5-R10). 64-code steps put
// 2x MFMA work (48/wave, two independent single-C chains) under each step's
// overhead. 2 x 32KB LDS buffers; stage(t+1) issued after barrier into the
// buffer consumed at step t-1 (race-safe, same argument as the 3-ring).
__global__ __launch_bounds__(512) void argmin_kernel(
        const ushort_t* __restrict__ apk, const ushort_t* __restrict__ bpk,
        const float* __restrict__ esq, u64* __restrict__ keys,
        int tiles, int slices) {
    __shared__ ushort_t lds[2][16384];   // 2 x 32 KB
    __shared__ float es_lds[2048];

    int cps = NCODES / slices;
    int steps = cps >> 6;
    int bid = blockIdx.x;
    // tile = bid/slices, slice = bid%slices: XCD x (bid%8==x) sees slices
    // {x mod slices} only (slices | 8) or a small fixed set -> L2-clean.
    int tile  = bid / slices;
    int slice = bid % slices;
    int code0 = slice * cps;
    int tid = threadIdx.x, wv = tid >> 6, l = tid & 63, l31 = l & 31, lh = l >> 5;

    // A fragments: one 32-row tile per wave (16 VMEM loads, 64 VGPR)
    int rb = tile * 8 + wv;
    const ushort_t* ap = apk + (size_t)rb * 8192 + l * 8;
    bf16x8 a_h[8], a_l[8];
    #pragma unroll
    for (int c = 0; c < 8; c++) {
        a_h[c] = *(const bf16x8*)(ap + (2 * c) * 512);
        a_l[c] = *(const bf16x8*)(ap + (2 * c + 1) * 512);
    }
    float ev0 = 0.f, ev1 = 0.f, ev2 = 0.f, ev3 = 0.f;
    if (tid < cps)        ev0 = esq[code0 + tid];
    if (512  + tid < cps) ev1 = esq[code0 + 512 + tid];
    if (1024 + tid < cps) ev2 = esq[code0 + 1024 + tid];
    if (1536 + tid < cps) ev3 = esq[code0 + 1536 + tid];
    __builtin_amdgcn_sched_barrier(0);   // pin: A+esq issue before staging

    const char* bbase = (const char*)bpk + (size_t)(code0 >> 6) * 32768;
    {   // prologue: stage step 0 into buf 0 (4 x 1KB per wave)
        const char* g0 = bbase + (size_t)wv * 4096 + (size_t)l * 16;
        ushort_t* d0 = &lds[0][wv * 2048];
        gload_lds16(g0,        d0);
        gload_lds16(g0 + 1024, d0 + 512);
        gload_lds16(g0 + 2048, d0 + 1024);
        gload_lds16(g0 + 3072, d0 + 1536);
    }
    __builtin_amdgcn_sched_barrier(0);
    if (tid < cps)        es_lds[tid] = ev0;
    if (512  + tid < cps) es_lds[512 + tid] = ev1;
    if (1024 + tid < cps) es_lds[1024 + tid] = ev2;
    if (1536 + tid < cps) es_lds[1536 + tid] = ev3;
    asm volatile("s_waitcnt lgkmcnt(0)" ::: "memory");

    float best[16];
    int   bidx[16];
    #pragma unroll
    for (int r = 0; r < 16; r++) { best[r] = 1e38f; bidx[r] = 0; }

    for (int t = 0; t < steps; ++t) {
        asm volatile("s_waitcnt vmcnt(0)" ::: "memory");  // own stage(t) landed
        __builtin_amdgcn_s_barrier();    // buf[t&1] fully staged; buf[(t+1)&1] free
        if (t + 1 < steps) {             // stage t+1 (consumed-at-t-1 buffer)
            const char* g = bbase + (size_t)(t + 1) * 32768
                          + (size_t)wv * 4096 + (size_t)l * 16;
            ushort_t* d = &lds[(t + 1) & 1][wv * 2048];
            gload_lds16(g,        d);
            gload_lds16(g + 1024, d + 512);
            gload_lds16(g + 2048, d + 1024);
            gload_lds16(g + 3072, d + 1536);
        }
        float es0 = es_lds[(t << 6) + l31];
        float es1 = es_lds[(t << 6) + 32 + l31];
        f32x16 acc0, acc1;
        #pragma unroll
        for (int r = 0; r < 16; r++) { acc0[r] = es0; acc1[r] = es1; }
        const ushort_t* lp = &lds[t & 1][0] + l * 8;
        __builtin_amdgcn_s_setprio(1);
        #pragma unroll
        for (int c = 0; c < 8; c++) {
            bf16x8 g0h = *(const bf16x8*)(lp + (2 * c) * 512);
            bf16x8 g0l = *(const bf16x8*)(lp + (2 * c + 1) * 512);
            bf16x8 g1h = *(const bf16x8*)(lp + 8192 + (2 * c) * 512);
            bf16x8 g1l = *(const bf16x8*)(lp + 8192 + (2 * c + 1) * 512);
            acc0 = __builtin_amdgcn_mfma_f32_32x32x16_bf16(a_h[c], g0h, acc0, 0, 0, 0);
            acc1 = __builtin_amdgcn_mfma_f32_32x32x16_bf16(a_h[c], g1h, acc1, 0, 0, 0);
            acc0 = __builtin_amdgcn_mfma_f32_32x32x16_bf16(a_h[c], g0l, acc0, 0, 0, 0);
            acc1 = __builtin_amdgcn_mfma_f32_32x32x16_bf16(a_h[c], g1l, acc1, 0, 0, 0);
            acc0 = __builtin_amdgcn_mfma_f32_32x32x16_bf16(a_l[c], g0h, acc0, 0, 0, 0);
            acc1 = __builtin_amdgcn_mfma_f32_32x32x16_bf16(a_l[c], g1h, acc1, 0, 0, 0);
        }
        __builtin_amdgcn_s_setprio(0);
        int code = code0 + (t << 6) + l31;
        #pragma unroll
        for (int r = 0; r < 16; r++) {
            float s0 = acc0[r], s1 = acc1[r];
            float m  = fminf(s0, s1);
            int   ci = (s0 <= s1) ? code : code + 32;   // tie -> lower index
            bool lt = m < best[r];
            best[r] = lt ? m : best[r];
            bidx[r] = lt ? ci : bidx[r];
        }
    }

    #pragma unroll
    for (int r = 0; r < 16; r++) {
        u32 fb = __float_as_uint(best[r]);
        fb = (fb & 0x80000000u) ? ~fb : (fb | 0x80000000u);
        u64 key = ((u64)fb << 32) | (u32)bidx[r];
        #pragma unroll
        for (int d = 1; d < 32; d <<= 1) {
            u64 o = __shfl_xor(key, d, 64);
            key = (o < key) ? o : key;
        }
        if (l31 == 0) {
            int rw = tile * 256 + wv * 32 + (r & 3) + 8 * (r >> 2) + 4 * lh;
            atomicMin(&keys[rw], key);
        }
    }
}

// ---------------- bicubic weight (a = -0.75) ----------------
__device__ __forceinline__ float cubicw(float t) {
    float t2 = t * t;
    if (t <= 1.0f) return (1.25f * t - 2.25f) * t2 + 1.0f;
    return -0.75f * (((t - 5.0f) * t + 8.0f) * t - 4.0f);
}

// ---------------- upsample + residual update + output + FUSED downsample ----------
__global__ __launch_bounds__(256) void up_kernel(
        const float* __restrict__ emb,
        const u64* __restrict__ keys,
        const float* __restrict__ src,   // z_enc (lvl0) or zrest
        const float* __restrict__ prev,  // out[lvl-1] (unused if first)
        float* __restrict__ zrest,
        float* __restrict__ out,
        float* __restrict__ zd_next,     // next level's zd (if pnn > 0)
        int pn, int last, int first, int pnn) {
    __shared__ float wtab[32][4];
    __shared__ int   itab[32][4];
    __shared__ float smp[512];
    int tid = threadIdx.x;
    if (!last && tid < 128) {
        int pos = tid >> 2, tap = tid & 3;
        float s  = (float)pn * (1.0f / 32.0f);
        float x  = ((float)pos + 0.5f) * s - 0.5f;
        float x0 = floorf(x);
        float t  = x - x0;
        int   off = tap - 1;
        float w  = cubicw(fabsf((float)off - t));
        int   jj = (int)x0 + off;
        jj = min(max(jj, 0), pn - 1);
        wtab[pos][tap] = w;
        itab[pos][tap] = jj;
    }
    __syncthreads();

    int t  = blockIdx.x * 256 + tid;
    int w4 = (t & 7) << 2;
    int h  = (t >> 3) & 31;
    int c  = (t >> 8) & 127;
    int b  = t >> 15;
    size_t i = (((size_t)b * CDIM + c) * 32 + h) * 32 + w4;

    float zu[4];
    if (last) {
        int kb = (b << 10) + (h << 5) + w4;
        #pragma unroll
        for (int j = 0; j < 4; j++) {
            int tok = (int)(keys[kb + j] & 0xFFFFFFFFull);
            zu[j] = emb[(size_t)tok * CDIM + c];
        }
    } else {
        int base = b * pn * pn;
        #pragma unroll
        for (int j = 0; j < 4; j++) zu[j] = 0.f;
        #pragma unroll
        for (int u = 0; u < 4; u++) {
            float whu = wtab[h][u];
            int   ih  = itab[h][u] * pn;
            #pragma unroll
            for (int j = 0; j < 4; j++) {
                float acc = 0.f;
                #pragma unroll
                for (int v = 0; v < 4; v++) {
                    int tok = (int)(keys[base + ih + itab[w4 + j][v]] & 0xFFFFFFFFull);
                    acc += wtab[w4 + j][v] * emb[(size_t)tok * CDIM + c];
                }
                zu[j] += whu * acc;
            }
        }
    }
    float4 sv = *(const float4*)(src + i);
    float4 pv = {0.f, 0.f, 0.f, 0.f};
    if (!first) pv = *(const float4*)(prev + i);
    float4 ov, rv;
    ov.x = pv.x + zu[0]; ov.y = pv.y + zu[1]; ov.z = pv.z + zu[2]; ov.w = pv.w + zu[3];
    rv.x = sv.x - zu[0]; rv.y = sv.y - zu[1]; rv.z = sv.z - zu[2]; rv.w = sv.w - zu[3];
    *(float4*)(out + i)   = ov;
    *(float4*)(zrest + i) = rv;

    if (pnn) {   // fused area-downsample of rv for next level
        int f = 32 / pnn;
        if (f >= 4) {
            smp[h * 8 + (w4 >> 2)] = (rv.x + rv.y) + (rv.z + rv.w);
        } else {  // f == 2
            smp[h * 16 + (w4 >> 1)]     = rv.x + rv.y;
            smp[h * 16 + (w4 >> 1) + 1] = rv.z + rv.w;
        }
        __syncthreads();
        int W = pnn * pnn;
        if (tid < W) {
            int lb = __builtin_ctz(pnn);
            int ph = tid >> lb, pw = tid & (pnn - 1);
            float s = 0.f;
            if (f >= 4) {
                int cg = f >> 2;
                for (int u = 0; u < f; u++)
                    for (int v = 0; v < cg; v++)
                        s += smp[(ph * f + u) * 8 + pw * cg + v];
            } else {
                s = smp[(2 * ph) * 16 + pw] + smp[(2 * ph + 1) * 16 + pw];
            }
            int b2 = blockIdx.x >> 7, c2 = blockIdx.x & 127;
            int row = (b2 * pnn + ph) * pnn + pw;
            zd_next[(size_t)row * CDIM + c2] = s * (1.0f / (float)(f * f));
        }
    }
}

extern "C" void kernel_launch(void* const* d_in, const int* in_sizes, int n_in,
                              void* d_out, int out_size, void* d_ws, size_t ws_size,
                              hipStream_t stream) {
    const float* z_enc = (const float*)d_in[0];
    const float* emb   = (const float*)d_in[1];
    float* out = (float*)d_out;
    float* ws  = (float*)d_ws;

    // ws layout (float offsets)
    float*    zrest  = ws;                                // 2,097,152
    float*    zd_f32 = ws + 2097152;                      // 2,097,152
    ushort_t* zd_pk  = (ushort_t*)(ws + 4194304);         // 4,194,304 ushort
    ushort_t* emb_pk = (ushort_t*)(ws + 6291456);         // 2,097,152 ushort
    float*    esq    = ws + 7340032;                      // 8192
    u64*      keys   = (u64*)(ws + 7348224);              // 16384 u64

    pack_emb_kernel<<<NCODES / 32, 256, 0, stream>>>(emb, emb_pk, esq);
    down_kernel<<<512, 256, 0, stream>>>(z_enc, zd_f32, 5);   // level-0 prep

    const int MS_[6] = {1, 2, 4, 8, 16, 32};
    const int SL_[6] = {128, 128, 128, 64, 16, 4};   // cps = {64,64,64,128,512,2048}
    for (int lvl = 0; lvl < 6; lvl++) {
        int pn     = MS_[lvl];
        int rows   = 16 * pn * pn;
        int tiles  = (rows + 255) / 256;
        int slices = SL_[lvl];
        const float* src = lvl ? zrest : z_enc;

        if (lvl < 5) {
            pack_kernel<<<tiles * 8, 256, 0, stream>>>(zd_f32, zd_pk, keys, rows, -2.0f);
        } else {
            pack_l5_kernel<<<512, 256, 0, stream>>>(zrest, zd_pk, keys);
        }
        argmin_kernel<<<tiles * slices, 512, 0, stream>>>(
            zd_pk, emb_pk, esq, keys, tiles, slices);
        int pnn = (lvl < 4) ? MS_[lvl + 1] : 0;
        up_kernel<<<NTOT / 4 / 256, 256, 0, stream>>>(
            emb, keys, src, lvl ? (out + (size_t)(lvl - 1) * NTOT) : out,
            zrest, out + (size_t)lvl * NTOT, zd_f32,
            pn, lvl == 5 ? 1 : 0, lvl == 0 ? 1 : 0, pnn);
    }
}